// Round 5
// baseline (363.182 us; speedup 1.0000x reference)
//
#include <hip/hip_runtime.h>
#include <math.h>

// Problem constants
#define N384 384
#define NPIX 147456            // 384*384
#define LSTRIDE 385            // padded LDS line stride (float2) to break bank alignment
#define LINES 8                // lines (rows or cols) per block

__device__ __forceinline__ float2 cmul(float2 a, float2 b) {
    return make_float2(a.x*b.x - a.y*b.y, a.x*b.y + a.y*b.x);
}

// ---------------------------------------------------------------------------
// Build LDS twiddle table tw[k] = (cos, sin)(2*pi*k/384), k in [0,384).
// ---------------------------------------------------------------------------
__device__ __forceinline__ void build_tw(float2* tw, int tid) {
    for (int k = tid; k < 384; k += 256) {
        float sn, cs;
        sincospif((float)k * (2.0f / 384.0f), &sn, &cs);
        tw[k] = make_float2(cs, sn);
    }
}

// ---------------------------------------------------------------------------
// In-LDS batched 384-point Stockham FFT, 8 lines per 256-thread block.
// 4 stages: R6(s=1), R4(s=6), R4(s=24), R4(s=96, twiddle-free).
// Returns the buffer holding the result.
// Caller must __syncthreads() after loading b0 + building tw.
// ---------------------------------------------------------------------------
template <int SGNI>
__device__ float2* fft384x8(float2* b0, float2* b1, const float2* tw, int tid) {
    float2* src = b0;
    float2* dst = b1;
    const int line = tid >> 5;   // 0..7
    const int l32  = tid & 31;   // 0..31
    const float SG = (float)SGNI;
    const float s3 = SG * 0.86602540378443864676f;

    // ---- radix-6 stage: s=1, 64 butterflies/line ----
    {
        float2* L = src + line * LSTRIDE;
        float2* D = dst + line * LSTRIDE;
#pragma unroll
        for (int q = 0; q < 2; ++q) {
            int i = l32 + 32 * q;                  // 0..63
            float2 e0 = L[i],       e1 = L[i + 128], e2 = L[i + 256];
            float2 o0 = L[i + 64],  o1 = L[i + 192], o2 = L[i + 320];
            // dft3(e0,e1,e2)
            float t1x = e1.x + e2.x, t1y = e1.y + e2.y;
            float t2x = e1.x - e2.x, t2y = e1.y - e2.y;
            float2 E0 = make_float2(e0.x + t1x, e0.y + t1y);
            float mx = e0.x - 0.5f * t1x, my = e0.y - 0.5f * t1y;
            float ux = -s3 * t2y, uy = s3 * t2x;
            float2 E1 = make_float2(mx + ux, my + uy);
            float2 E2 = make_float2(mx - ux, my - uy);
            // dft3(o0,o1,o2)
            float s1x = o1.x + o2.x, s1y = o1.y + o2.y;
            float s2x = o1.x - o2.x, s2y = o1.y - o2.y;
            float2 O0 = make_float2(o0.x + s1x, o0.y + s1y);
            float nx = o0.x - 0.5f * s1x, ny = o0.y - 0.5f * s1y;
            float vx = -s3 * s2y, vy = s3 * s2x;
            float2 O1 = make_float2(nx + vx, ny + vy);
            float2 O2 = make_float2(nx - vx, ny - vy);
            float2 T1 = make_float2(0.5f * O1.x - s3 * O1.y, 0.5f * O1.y + s3 * O1.x);
            float2 T2 = make_float2(-0.5f * O2.x - s3 * O2.y, -0.5f * O2.y + s3 * O2.x);
            float2 y0 = make_float2(E0.x + O0.x, E0.y + O0.y);
            float2 y3 = make_float2(E0.x - O0.x, E0.y - O0.y);
            float2 y1 = make_float2(E1.x + T1.x, E1.y + T1.y);
            float2 y4 = make_float2(E1.x - T1.x, E1.y - T1.y);
            float2 y2 = make_float2(E2.x + T2.x, E2.y + T2.y);
            float2 y5 = make_float2(E2.x - T2.x, E2.y - T2.y);
            float2 c1 = tw[i], c2 = tw[2 * i], c3 = tw[3 * i], c4 = tw[4 * i], c5 = tw[5 * i];
            int o = 6 * i;
            D[o]     = y0;
            D[o + 1] = cmul(y1, make_float2(c1.x, SG * c1.y));
            D[o + 2] = cmul(y2, make_float2(c2.x, SG * c2.y));
            D[o + 3] = cmul(y3, make_float2(c3.x, SG * c3.y));
            D[o + 4] = cmul(y4, make_float2(c4.x, SG * c4.y));
            D[o + 5] = cmul(y5, make_float2(c5.x, SG * c5.y));
        }
    }
    __syncthreads();
    { float2* t = src; src = dst; dst = t; }

    // ---- 2 twiddled radix-4 stages: s = 6, 24; 96 butterflies/line ----
#pragma unroll
    for (int st = 0; st < 2; ++st) {
        const int s = (st == 0) ? 6 : 24;          // compile-time
        float2* L = src + line * LSTRIDE;
        float2* D = dst + line * LSTRIDE;
#pragma unroll
        for (int q = 0; q < 3; ++q) {
            int i = l32 + 32 * q;                  // 0..95
            int k = i % s;                         // const-div (s compile-time)
            int js = i - k;                        // j*s
            float2 A0 = L[i];
            float2 A1 = L[i + 96];
            float2 A2 = L[i + 192];
            float2 A3 = L[i + 288];
            float t0x = A0.x + A2.x, t0y = A0.y + A2.y;
            float t1x = A0.x - A2.x, t1y = A0.y - A2.y;
            float t2x = A1.x + A3.x, t2y = A1.y + A3.y;
            float t3x = A1.x - A3.x, t3y = A1.y - A3.y;
            float u3x = -SG * t3y,   u3y = SG * t3x;   // SGN*i*t3
            float2 y0 = make_float2(t0x + t2x, t0y + t2y);
            float2 y2 = make_float2(t0x - t2x, t0y - t2y);
            float2 y1 = make_float2(t1x + u3x, t1y + u3y);
            float2 y3 = make_float2(t1x - u3x, t1y - u3y);
            float2 c1 = tw[js], c2 = tw[2 * js], c3 = tw[3 * js];
            float2 w1 = make_float2(c1.x, SG * c1.y);
            float2 w2 = make_float2(c2.x, SG * c2.y);
            float2 w3 = make_float2(c3.x, SG * c3.y);
            int o = i + 3 * js;                    // k + 4*j*s
            D[o]         = y0;
            D[o + s]     = cmul(y1, w1);
            D[o + 2 * s] = cmul(y2, w2);
            D[o + 3 * s] = cmul(y3, w3);
        }
        __syncthreads();
        { float2* t = src; src = dst; dst = t; }
    }

    // ---- final radix-4 stage: s=96, j=0, twiddle-free ----
    {
        float2* L = src + line * LSTRIDE;
        float2* D = dst + line * LSTRIDE;
#pragma unroll
        for (int q = 0; q < 3; ++q) {
            int i = l32 + 32 * q;                  // 0..95
            float2 A0 = L[i];
            float2 A1 = L[i + 96];
            float2 A2 = L[i + 192];
            float2 A3 = L[i + 288];
            float t0x = A0.x + A2.x, t0y = A0.y + A2.y;
            float t1x = A0.x - A2.x, t1y = A0.y - A2.y;
            float t2x = A1.x + A3.x, t2y = A1.y + A3.y;
            float t3x = A1.x - A3.x, t3y = A1.y - A3.y;
            float u3x = -SG * t3y,   u3y = SG * t3x;
            D[i]       = make_float2(t0x + t2x, t0y + t2y);
            D[i + 96]  = make_float2(t1x + u3x, t1y + u3y);
            D[i + 192] = make_float2(t0x - t2x, t0y - t2y);
            D[i + 288] = make_float2(t1x - u3x, t1y - u3y);
        }
    }
    __syncthreads();
    return dst;
}

// ---------------------------------------------------------------------------
// K1: forward row FFT of x (real input), 2 rows packed per complex FFT.
// Store only bins k < 192 (downstream reads only those).
// ---------------------------------------------------------------------------
__global__ __launch_bounds__(256) void k_fwd_rows(const float* __restrict__ x,
                                                  float2* __restrict__ F1) {
    __shared__ float2 sbuf[2][LINES * LSTRIDE];
    __shared__ float2 tw[384];
    int img = blockIdx.y;
    int rg  = blockIdx.x;                          // 0..23
    int tid = threadIdx.x;
    build_tw(tw, tid);
    const float4* xim = (const float4*)(x + (size_t)img * NPIX + (size_t)rg * 16 * 384);
    for (int idx4 = tid; idx4 < 1536; idx4 += 256) {   // 16 rows * 96 float4
        int row = idx4 / 96;                       // 0..15
        int e   = (idx4 - row * 96) * 4;
        float4 v = xim[idx4];
        float* L = (float*)(sbuf[0] + (row >> 1) * LSTRIDE + e) + (row & 1);
        L[0] = v.x; L[2] = v.y; L[4] = v.z; L[6] = v.w;
    }
    __syncthreads();
    float2* res = fft384x8<-1>(sbuf[0], sbuf[1], tw, tid);
    float2* F1b = F1 + (size_t)img * NPIX + (size_t)rg * 16 * 384;
    for (int it = tid; it < 1536; it += 256) {     // 8 lines * 192 bins
        int line = it / 192;
        int k2   = it - line * 192;
        const float2* L = res + line * LSTRIDE;
        float2 A = L[k2];
        int m = (k2 == 0) ? 0 : 384 - k2;
        float2 B = L[m];
        float2 X1 = make_float2(0.5f * (A.x + B.x), 0.5f * (A.y - B.y));
        float2 X2 = make_float2(0.5f * (A.y + B.y), 0.5f * (B.x - A.x));
        F1b[(size_t)(2 * line) * 384 + k2]     = X1;
        F1b[(size_t)(2 * line + 1) * 384 + k2] = X2;
    }
}

// ---------------------------------------------------------------------------
// K2: forward column FFT. 24 col-groups; only rows h < 192 stored.
// ---------------------------------------------------------------------------
__global__ __launch_bounds__(256) void k_fwd_cols(const float2* __restrict__ In,
                                                  float2* __restrict__ Out) {
    __shared__ float2 sbuf[2][LINES * LSTRIDE];
    __shared__ float2 tw[384];
    int img = blockIdx.y;
    int cg  = blockIdx.x;                          // 0..23
    int tid = threadIdx.x;
    build_tw(tw, tid);
    const float4* inim = (const float4*)(In + (size_t)img * NPIX + cg * 8);
    int c = tid & 3, hb = tid >> 2;                // c: float4 (2 cols), hb: 0..63
    for (int q = 0; q < 6; ++q) {
        int h = hb + 64 * q;
        float4 v = inim[(size_t)h * 192 + c];
        sbuf[0][(2 * c) * LSTRIDE + h]     = make_float2(v.x, v.y);
        sbuf[0][(2 * c + 1) * LSTRIDE + h] = make_float2(v.z, v.w);
    }
    __syncthreads();
    float2* res = fft384x8<-1>(sbuf[0], sbuf[1], tw, tid);
    float4* outim = (float4*)(Out + (size_t)img * NPIX + cg * 8);
    for (int q = 0; q < 3; ++q) {                  // store h < 192 only
        int h = hb + 64 * q;
        float2 a = res[(2 * c) * LSTRIDE + h];
        float2 b = res[(2 * c + 1) * LSTRIDE + h];
        outim[(size_t)h * 192 + c] = make_float4(a.x, a.y, b.x, b.y);
    }
}

// ---------------------------------------------------------------------------
// K3: per-pixel attention MLP + log-Gabor filter bank -> attended[4,H,W]
// (shifted frame), quadrant-restricted with per-wave ballot early-exit.
// ---------------------------------------------------------------------------
__global__ __launch_bounds__(192) void k_attn(const float2* __restrict__ F2,
                                              const float* __restrict__ theta,
                                              const float* __restrict__ sigma,
                                              const float* __restrict__ f0,
                                              const float* __restrict__ theta0,
                                              const float* __restrict__ aw1,
                                              const float* __restrict__ ab1,
                                              const float* __restrict__ aw2,
                                              const float* __restrict__ ab2,
                                              const float* __restrict__ band,
                                              float2* __restrict__ A) {
    __shared__ float4 par[27];     // (lf0, -1/(2 ln^2 sigma), theta, -1/(2 theta0^2))
    int tid = threadIdx.x;
    if (tid < 27) {
        float lf0 = logf(f0[tid]);
        float ls  = logf(sigma[tid]);
        float na  = -0.5f / (ls * ls);
        float th  = theta[tid];
        float t0  = theta0[tid];
        float nb  = -0.5f / (t0 * t0);
        par[tid] = make_float4(lf0, na, th, nb);
    }
    __syncthreads();               // (must precede any early return)

    int h = 192 + blockIdx.x;      // [192,384)
    int w = 192 + tid;             // [192,384)

    bool needed = false;
#pragma unroll
    for (int q = 0; q < 9; ++q) {
        int s = (int)floorf((band[2 * q + 0] + 1.0f) * 0.5f * 384.0f);
        int e = (int)floorf((band[2 * q + 1] + 1.0f) * 0.5f * 384.0f);
        needed |= (h >= s) && (h < e) && (w >= s) && (w < e);
    }
    if (__ballot(needed) == 0ULL) return;   // whole wave dead

    int hs = h - 192;              // F2 source coords (shifted back)
    int ws = w - 192;

    float2 xf[4][3];
    float  mag[4][3];
#pragma unroll
    for (int b = 0; b < 4; ++b) {
        int bp = (b + 2) & 3;
#pragma unroll
        for (int c = 0; c < 3; ++c) {
            int cp = c + 2; if (cp >= 3) cp -= 3;
            float2 v = F2[(size_t)(bp * 3 + cp) * NPIX + (size_t)hs * 384 + ws];
            xf[b][c]  = v;
            mag[b][c] = sqrtf(v.x * v.x + v.y * v.y);
        }
    }

    float lgt[4][9];
#pragma unroll
    for (int b = 0; b < 4; ++b)
#pragma unroll
        for (int j = 0; j < 9; ++j) lgt[b][j] = ab2[j];
    for (int o = 0; o < 64; ++o) {
        float w0 = aw1[o * 3 + 0], w1 = aw1[o * 3 + 1], w2 = aw1[o * 3 + 2];
        float bb = ab1[o];
        float hv[4];
#pragma unroll
        for (int b = 0; b < 4; ++b)
            hv[b] = fmaxf(bb + w0 * mag[b][0] + w1 * mag[b][1] + w2 * mag[b][2], 0.0f);
#pragma unroll
        for (int j = 0; j < 9; ++j) {
            float wj = aw2[j * 64 + o];
#pragma unroll
            for (int b = 0; b < 4; ++b) lgt[b][j] += wj * hv[b];
        }
    }

    float yy = -1.0f + 2.0f * (float)h / 383.0f;
    float xx = -1.0f + 2.0f * (float)w / 383.0f;
    float r   = sqrtf(xx * xx + yy * yy + 1e-6f);
    float phi = atan2f(yy, xx);
    float filt[27];
#pragma unroll
    for (int i = 0; i < 27; ++i) {
        float4 pr = par[i];                 // LDS broadcast
        float lr = logf(r - pr.x);
        float dphi = phi - pr.z;
        filt[i] = expf(lr * lr * pr.y + dphi * dphi * pr.w);
    }

#pragma unroll
    for (int b = 0; b < 4; ++b) {
        float mxv = lgt[b][0];
#pragma unroll
        for (int j = 1; j < 9; ++j) mxv = fmaxf(mxv, lgt[b][j]);
        float e[9];
        float se = 0.0f;
#pragma unroll
        for (int j = 0; j < 9; ++j) { e[j] = expf(lgt[b][j] - mxv); se += e[j]; }
        float inv = 1.0f / se;

        float2 acc = make_float2(0.0f, 0.0f);
#pragma unroll
        for (int d = 0; d < 3; ++d) {
            float wg = 0.0f;
#pragma unroll
            for (int s = 0; s < 3; ++s)
#pragma unroll
                for (int co = 0; co < 3; ++co)
                    wg += e[s * 3 + co] * filt[(s * 3 + co) * 3 + d];
            wg *= inv;
            acc.x += xf[b][d].x * wg;
            acc.y += xf[b][d].y * wg;
        }
        if (needed)
            A[(size_t)b * NPIX + (size_t)h * 384 + w] = acc;
    }
}

// ---------------------------------------------------------------------------
// K4': masked inverse ROW FFTs, band rows only, compact output.
// G1c[ii][h'-sidx][w] stores (-1)^w * row-ifft (unnormalized), all 384 w
// (w outside band cols already zeroed at the masked load).
// ---------------------------------------------------------------------------
__global__ __launch_bounds__(256) void k_masked_rows(const float2* __restrict__ A,
                                                     const float* __restrict__ band,
                                                     float2* __restrict__ G1c) {
    int ii  = blockIdx.y;                  // 0..35
    int rg  = blockIdx.x;                  // 0..23
    int cop = ii / 12;
    int bp  = (ii / 3) % 4;
    int dp  = ii % 3;
    int pidx = (cop * 3 + dp) * 2;
    int sidx = (int)floorf((band[pidx + 0] + 1.0f) * 0.5f * 384.0f);
    int eidx = (int)floorf((band[pidx + 1] + 1.0f) * 0.5f * 384.0f);
    if (eidx <= sidx) return;
    int h0 = 192 + rg * 8;
    if (h0 + 8 <= sidx || h0 >= eidx) return;

    __shared__ float2 sbuf[2][LINES * LSTRIDE];
    __shared__ float2 tw[384];
    int tid = threadIdx.x;
    build_tw(tw, tid);
    const float2* Ab = A + (size_t)bp * NPIX;
    for (int idx = tid; idx < 8 * 384; idx += 256) {
        int line = idx / 384;
        int w    = idx - line * 384;
        int h    = h0 + line;
        bool m = (h >= sidx) && (h < eidx) && (w >= sidx) && (w < eidx);
        float2 v = make_float2(0.0f, 0.0f);
        if (m) v = Ab[(size_t)h * 384 + w];
        sbuf[0][line * LSTRIDE + w] = v;
    }
    __syncthreads();
    float2* res = fft384x8<1>(sbuf[0], sbuf[1], tw, tid);
    for (int idx = tid; idx < 8 * 384; idx += 256) {
        int line = idx / 384;
        int w    = idx - line * 384;
        int h    = h0 + line;
        if (h >= sidx && h < eidx) {
            float2 v = res[line * LSTRIDE + w];
            if (w & 1) { v.x = -v.x; v.y = -v.y; }
            G1c[((size_t)ii * 192 + (h - sidx)) * 384 + w] = v;
        }
    }
}

// ---------------------------------------------------------------------------
// K5''': column inverse FFT (replaces the O(rows*384) column DFT) + combine
// + inline 3x3 conv (o=d quirk). Block = (ii, 8-col group). Band rows are
// placed at their true frequency positions in LDS (zeros elsewhere) and one
// fft384x8<+1> produces acc[h] for all 384 h at once. Uniform per-block cost
// (no band-length imbalance); empty-band blocks skip the FFT.
// ---------------------------------------------------------------------------
__global__ __launch_bounds__(256) void k_col_ifft_combine(const float2* __restrict__ G1c,
                                                          const float* __restrict__ band,
                                                          const float* __restrict__ x,
                                                          const float* __restrict__ cw,
                                                          const float* __restrict__ mixing,
                                                          float* __restrict__ out) {
    __shared__ float2 sbuf[2][LINES * LSTRIDE];
    __shared__ float2 tw[384];
    int tid = threadIdx.x;
    int ii  = blockIdx.y;                  // 0..35
    int cg  = blockIdx.x;                  // 0..47
    int w0  = cg * 8;

    int cop = ii / 12;
    int bp  = (ii / 3) % 4;
    int dp  = ii % 3;
    int pidx = (cop * 3 + dp) * 2;
    int sidx = (int)floorf((band[pidx + 0] + 1.0f) * 0.5f * 384.0f);
    int eidx = (int)floorf((band[pidx + 1] + 1.0f) * 0.5f * 384.0f);
    bool hasband = (eidx > sidx);          // block-uniform

    float2* res = sbuf[0];
    if (hasband) {
        build_tw(tw, tid);
        const float2* gb = G1c + (size_t)ii * 192 * 384 + w0;
        // place band rows at true positions, zeros elsewhere (one pass)
        for (int idx = tid; idx < 8 * 384; idx += 256) {
            int c = idx & 7;
            int p = idx >> 3;              // 0..383 (frequency position)
            float2 v = make_float2(0.0f, 0.0f);
            if (p >= sidx && p < eidx)
                v = gb[(size_t)(p - sidx) * 384 + c];
            sbuf[0][c * LSTRIDE + p] = v;
        }
        __syncthreads();
        res = fft384x8<1>(sbuf[0], sbuf[1], tw, tid);
    }

    int co = cop + 2; if (co >= 3) co -= 3;
    int b  = (bp + 2) & 3;
    int d  = dp + 2;  if (d >= 3) d -= 3;

    // hoist conv weights (uniform per block -> scalar regs)
    float wv[3][9];
#pragma unroll
    for (int ci = 0; ci < 3; ++ci)
#pragma unroll
        for (int t = 0; t < 9; ++t) wv[ci][t] = cw[((size_t)d * 3 + ci) * 9 + t];

    float mix  = mixing[0];
    float omix = 1.0f - mix;
    const float invn2 = 1.0f / 147456.0f;
    const float* xb = x + (size_t)b * 3 * NPIX;
    float* obase = out + (size_t)(co * 12 + b * 3 + d) * NPIX;

    // 3072 pixels / 256 threads = 12 per thread
    for (int q = 0; q < 12; ++q) {
        int p = q * 256 + tid;
        int h = p >> 3;                    // 0..383
        int c = p & 7;
        int w = w0 + c;

        float accre = hasband ? res[c * LSTRIDE + h].x : 0.0f;
        float sgn = (h & 1) ? -invn2 : invn2;   // fold (-1)^h / N^2

        // 3x3 conv at (h, w), zero pad
        float cv = 0.0f;
#pragma unroll
        for (int ci = 0; ci < 3; ++ci) {
            const float* xc = xb + (size_t)ci * NPIX;
#pragma unroll
            for (int kh = 0; kh < 3; ++kh) {
                int hh = h + kh - 1;
                if (hh < 0 || hh >= 384) continue;
                const float* xr = xc + (size_t)hh * 384;
#pragma unroll
                for (int kw = 0; kw < 3; ++kw) {
                    int ww = w + kw - 1;
                    if (ww >= 0 && ww < 384)
                        cv += xr[ww] * wv[ci][kh * 3 + kw];
                }
            }
        }

        float val = mix * (accre * sgn) + omix * cv;
        size_t off = (size_t)h * 384 + w;
#pragma unroll
        for (int a = 0; a < 4; ++a)
            obase[off + (size_t)a * 5308416] = val;   // a stride = 36*NPIX
    }
}

// ---------------------------------------------------------------------------
extern "C" void kernel_launch(void* const* d_in, const int* in_sizes, int n_in,
                              void* d_out, int out_size, void* d_ws, size_t ws_size,
                              hipStream_t stream) {
    const float* x      = (const float*)d_in[0];
    const float* theta  = (const float*)d_in[1];
    const float* sigma  = (const float*)d_in[2];
    const float* f0     = (const float*)d_in[3];
    const float* theta0 = (const float*)d_in[4];
    const float* aw1    = (const float*)d_in[5];
    const float* ab1    = (const float*)d_in[6];
    const float* aw2    = (const float*)d_in[7];
    const float* ab2    = (const float*)d_in[8];
    const float* cw     = (const float*)d_in[9];
    const float* mixing = (const float*)d_in[10];
    const float* band   = (const float*)d_in[11];
    float* out = (float*)d_out;

    // Workspace layout (float2 units), with reuse:
    //   [0, 12*NPIX)   F1 (dead after K2)   \  overlaid by G1c [0, 18*NPIX)
    //   [12, 24*NPIX)  F2 (dead after K3)   /
    //   [36, 40*NPIX)  A  (attended, shifted frame)
    float2* F1  = (float2*)d_ws;
    float2* F2  = F1 + (size_t)12 * NPIX;
    float2* G1c = (float2*)d_ws;
    float2* A   = (float2*)d_ws + (size_t)36 * NPIX;

    k_fwd_rows<<<dim3(24, 12), 256, 0, stream>>>(x, F1);
    k_fwd_cols<<<dim3(24, 12), 256, 0, stream>>>(F1, F2);
    k_attn<<<192, 192, 0, stream>>>(F2, theta, sigma, f0, theta0,
                                    aw1, ab1, aw2, ab2, band, A);
    k_masked_rows<<<dim3(24, 36), 256, 0, stream>>>(A, band, G1c);
    k_col_ifft_combine<<<dim3(48, 36), 256, 0, stream>>>(G1c, band, x, cw, mixing, out);
}

// Round 6
// 201.187 us; speedup vs baseline: 1.8052x; 1.8052x over previous
//
#include <hip/hip_runtime.h>
#include <math.h>

// Problem constants
#define N384 384
#define NPIX 147456            // 384*384
#define LSTRIDE 385            // padded LDS line stride (float2) to break bank alignment
#define LINES 8                // lines (rows or cols) per block

__device__ __forceinline__ float2 cmul(float2 a, float2 b) {
    return make_float2(a.x*b.x - a.y*b.y, a.x*b.y + a.y*b.x);
}

// ---------------------------------------------------------------------------
// Build LDS twiddle table tw[k] = (cos, sin)(2*pi*k/384), k in [0,384).
// ---------------------------------------------------------------------------
template <int NT>
__device__ __forceinline__ void build_tw(float2* tw, int tid) {
    for (int k = tid; k < 384; k += NT) {
        float sn, cs;
        sincospif((float)k * (2.0f / 384.0f), &sn, &cs);
        tw[k] = make_float2(cs, sn);
    }
}

// ---------------------------------------------------------------------------
// In-LDS batched 384-point Stockham FFT, 8 lines per 256-thread block.
// 4 stages: R6(s=1), R4(s=6), R4(s=24), R4(s=96, twiddle-free).
// Returns the buffer holding the result.
// Caller must __syncthreads() after loading b0 + building tw.
// ---------------------------------------------------------------------------
template <int SGNI>
__device__ float2* fft384x8(float2* b0, float2* b1, const float2* tw, int tid) {
    float2* src = b0;
    float2* dst = b1;
    const int line = tid >> 5;   // 0..7
    const int l32  = tid & 31;   // 0..31
    const float SG = (float)SGNI;
    const float s3 = SG * 0.86602540378443864676f;

    // ---- radix-6 stage: s=1, 64 butterflies/line ----
    {
        float2* L = src + line * LSTRIDE;
        float2* D = dst + line * LSTRIDE;
#pragma unroll
        for (int q = 0; q < 2; ++q) {
            int i = l32 + 32 * q;                  // 0..63
            float2 e0 = L[i],       e1 = L[i + 128], e2 = L[i + 256];
            float2 o0 = L[i + 64],  o1 = L[i + 192], o2 = L[i + 320];
            // dft3(e0,e1,e2)
            float t1x = e1.x + e2.x, t1y = e1.y + e2.y;
            float t2x = e1.x - e2.x, t2y = e1.y - e2.y;
            float2 E0 = make_float2(e0.x + t1x, e0.y + t1y);
            float mx = e0.x - 0.5f * t1x, my = e0.y - 0.5f * t1y;
            float ux = -s3 * t2y, uy = s3 * t2x;
            float2 E1 = make_float2(mx + ux, my + uy);
            float2 E2 = make_float2(mx - ux, my - uy);
            // dft3(o0,o1,o2)
            float s1x = o1.x + o2.x, s1y = o1.y + o2.y;
            float s2x = o1.x - o2.x, s2y = o1.y - o2.y;
            float2 O0 = make_float2(o0.x + s1x, o0.y + s1y);
            float nx = o0.x - 0.5f * s1x, ny = o0.y - 0.5f * s1y;
            float vx = -s3 * s2y, vy = s3 * s2x;
            float2 O1 = make_float2(nx + vx, ny + vy);
            float2 O2 = make_float2(nx - vx, ny - vy);
            float2 T1 = make_float2(0.5f * O1.x - s3 * O1.y, 0.5f * O1.y + s3 * O1.x);
            float2 T2 = make_float2(-0.5f * O2.x - s3 * O2.y, -0.5f * O2.y + s3 * O2.x);
            float2 y0 = make_float2(E0.x + O0.x, E0.y + O0.y);
            float2 y3 = make_float2(E0.x - O0.x, E0.y - O0.y);
            float2 y1 = make_float2(E1.x + T1.x, E1.y + T1.y);
            float2 y4 = make_float2(E1.x - T1.x, E1.y - T1.y);
            float2 y2 = make_float2(E2.x + T2.x, E2.y + T2.y);
            float2 y5 = make_float2(E2.x - T2.x, E2.y - T2.y);
            float2 c1 = tw[i], c2 = tw[2 * i], c3 = tw[3 * i], c4 = tw[4 * i], c5 = tw[5 * i];
            int o = 6 * i;
            D[o]     = y0;
            D[o + 1] = cmul(y1, make_float2(c1.x, SG * c1.y));
            D[o + 2] = cmul(y2, make_float2(c2.x, SG * c2.y));
            D[o + 3] = cmul(y3, make_float2(c3.x, SG * c3.y));
            D[o + 4] = cmul(y4, make_float2(c4.x, SG * c4.y));
            D[o + 5] = cmul(y5, make_float2(c5.x, SG * c5.y));
        }
    }
    __syncthreads();
    { float2* t = src; src = dst; dst = t; }

    // ---- 2 twiddled radix-4 stages: s = 6, 24; 96 butterflies/line ----
#pragma unroll
    for (int st = 0; st < 2; ++st) {
        const int s = (st == 0) ? 6 : 24;          // compile-time
        float2* L = src + line * LSTRIDE;
        float2* D = dst + line * LSTRIDE;
#pragma unroll
        for (int q = 0; q < 3; ++q) {
            int i = l32 + 32 * q;                  // 0..95
            int k = i % s;                         // const-div (s compile-time)
            int js = i - k;                        // j*s
            float2 A0 = L[i];
            float2 A1 = L[i + 96];
            float2 A2 = L[i + 192];
            float2 A3 = L[i + 288];
            float t0x = A0.x + A2.x, t0y = A0.y + A2.y;
            float t1x = A0.x - A2.x, t1y = A0.y - A2.y;
            float t2x = A1.x + A3.x, t2y = A1.y + A3.y;
            float t3x = A1.x - A3.x, t3y = A1.y - A3.y;
            float u3x = -SG * t3y,   u3y = SG * t3x;   // SGN*i*t3
            float2 y0 = make_float2(t0x + t2x, t0y + t2y);
            float2 y2 = make_float2(t0x - t2x, t0y - t2y);
            float2 y1 = make_float2(t1x + u3x, t1y + u3y);
            float2 y3 = make_float2(t1x - u3x, t1y - u3y);
            float2 c1 = tw[js], c2 = tw[2 * js], c3 = tw[3 * js];
            float2 w1 = make_float2(c1.x, SG * c1.y);
            float2 w2 = make_float2(c2.x, SG * c2.y);
            float2 w3 = make_float2(c3.x, SG * c3.y);
            int o = i + 3 * js;                    // k + 4*j*s
            D[o]         = y0;
            D[o + s]     = cmul(y1, w1);
            D[o + 2 * s] = cmul(y2, w2);
            D[o + 3 * s] = cmul(y3, w3);
        }
        __syncthreads();
        { float2* t = src; src = dst; dst = t; }
    }

    // ---- final radix-4 stage: s=96, j=0, twiddle-free ----
    {
        float2* L = src + line * LSTRIDE;
        float2* D = dst + line * LSTRIDE;
#pragma unroll
        for (int q = 0; q < 3; ++q) {
            int i = l32 + 32 * q;                  // 0..95
            float2 A0 = L[i];
            float2 A1 = L[i + 96];
            float2 A2 = L[i + 192];
            float2 A3 = L[i + 288];
            float t0x = A0.x + A2.x, t0y = A0.y + A2.y;
            float t1x = A0.x - A2.x, t1y = A0.y - A2.y;
            float t2x = A1.x + A3.x, t2y = A1.y + A3.y;
            float t3x = A1.x - A3.x, t3y = A1.y - A3.y;
            float u3x = -SG * t3y,   u3y = SG * t3x;
            D[i]       = make_float2(t0x + t2x, t0y + t2y);
            D[i + 96]  = make_float2(t1x + u3x, t1y + u3y);
            D[i + 192] = make_float2(t0x - t2x, t0y - t2y);
            D[i + 288] = make_float2(t1x - u3x, t1y - u3y);
        }
    }
    __syncthreads();
    return dst;
}

// ---------------------------------------------------------------------------
// K1: forward row FFT of x (real input), 2 rows packed per complex FFT.
// Store only bins k < 192 (downstream reads only those).
// ---------------------------------------------------------------------------
__global__ __launch_bounds__(256) void k_fwd_rows(const float* __restrict__ x,
                                                  float2* __restrict__ F1) {
    __shared__ float2 sbuf[2][LINES * LSTRIDE];
    __shared__ float2 tw[384];
    int img = blockIdx.y;
    int rg  = blockIdx.x;                          // 0..23
    int tid = threadIdx.x;
    build_tw<256>(tw, tid);
    const float4* xim = (const float4*)(x + (size_t)img * NPIX + (size_t)rg * 16 * 384);
    for (int idx4 = tid; idx4 < 1536; idx4 += 256) {   // 16 rows * 96 float4
        int row = idx4 / 96;                       // 0..15
        int e   = (idx4 - row * 96) * 4;
        float4 v = xim[idx4];
        float* L = (float*)(sbuf[0] + (row >> 1) * LSTRIDE + e) + (row & 1);
        L[0] = v.x; L[2] = v.y; L[4] = v.z; L[6] = v.w;
    }
    __syncthreads();
    float2* res = fft384x8<-1>(sbuf[0], sbuf[1], tw, tid);
    float2* F1b = F1 + (size_t)img * NPIX + (size_t)rg * 16 * 384;
    for (int it = tid; it < 1536; it += 256) {     // 8 lines * 192 bins
        int line = it / 192;
        int k2   = it - line * 192;
        const float2* L = res + line * LSTRIDE;
        float2 A = L[k2];
        int m = (k2 == 0) ? 0 : 384 - k2;
        float2 B = L[m];
        float2 X1 = make_float2(0.5f * (A.x + B.x), 0.5f * (A.y - B.y));
        float2 X2 = make_float2(0.5f * (A.y + B.y), 0.5f * (B.x - A.x));
        F1b[(size_t)(2 * line) * 384 + k2]     = X1;
        F1b[(size_t)(2 * line + 1) * 384 + k2] = X2;
    }
}

// ---------------------------------------------------------------------------
// K2: forward column FFT. 24 col-groups; only rows h < 192 stored.
// ---------------------------------------------------------------------------
__global__ __launch_bounds__(256) void k_fwd_cols(const float2* __restrict__ In,
                                                  float2* __restrict__ Out) {
    __shared__ float2 sbuf[2][LINES * LSTRIDE];
    __shared__ float2 tw[384];
    int img = blockIdx.y;
    int cg  = blockIdx.x;                          // 0..23
    int tid = threadIdx.x;
    build_tw<256>(tw, tid);
    const float4* inim = (const float4*)(In + (size_t)img * NPIX + cg * 8);
    int c = tid & 3, hb = tid >> 2;                // c: float4 (2 cols), hb: 0..63
    for (int q = 0; q < 6; ++q) {
        int h = hb + 64 * q;
        float4 v = inim[(size_t)h * 192 + c];
        sbuf[0][(2 * c) * LSTRIDE + h]     = make_float2(v.x, v.y);
        sbuf[0][(2 * c + 1) * LSTRIDE + h] = make_float2(v.z, v.w);
    }
    __syncthreads();
    float2* res = fft384x8<-1>(sbuf[0], sbuf[1], tw, tid);
    float4* outim = (float4*)(Out + (size_t)img * NPIX + cg * 8);
    for (int q = 0; q < 3; ++q) {                  // store h < 192 only
        int h = hb + 64 * q;
        float2 a = res[(2 * c) * LSTRIDE + h];
        float2 b = res[(2 * c + 1) * LSTRIDE + h];
        outim[(size_t)h * 192 + c] = make_float4(a.x, a.y, b.x, b.y);
    }
}

// ---------------------------------------------------------------------------
// K3: per-pixel attention MLP + log-Gabor filter bank -> attended[4,H,W]
// (shifted frame), quadrant-restricted with per-wave ballot early-exit.
// ---------------------------------------------------------------------------
__global__ __launch_bounds__(192) void k_attn(const float2* __restrict__ F2,
                                              const float* __restrict__ theta,
                                              const float* __restrict__ sigma,
                                              const float* __restrict__ f0,
                                              const float* __restrict__ theta0,
                                              const float* __restrict__ aw1,
                                              const float* __restrict__ ab1,
                                              const float* __restrict__ aw2,
                                              const float* __restrict__ ab2,
                                              const float* __restrict__ band,
                                              float2* __restrict__ A) {
    __shared__ float4 par[27];     // (lf0, -1/(2 ln^2 sigma), theta, -1/(2 theta0^2))
    int tid = threadIdx.x;
    if (tid < 27) {
        float lf0 = logf(f0[tid]);
        float ls  = logf(sigma[tid]);
        float na  = -0.5f / (ls * ls);
        float th  = theta[tid];
        float t0  = theta0[tid];
        float nb  = -0.5f / (t0 * t0);
        par[tid] = make_float4(lf0, na, th, nb);
    }
    __syncthreads();               // (must precede any early return)

    int h = 192 + blockIdx.x;      // [192,384)
    int w = 192 + tid;             // [192,384)

    bool needed = false;
#pragma unroll
    for (int q = 0; q < 9; ++q) {
        int s = (int)floorf((band[2 * q + 0] + 1.0f) * 0.5f * 384.0f);
        int e = (int)floorf((band[2 * q + 1] + 1.0f) * 0.5f * 384.0f);
        needed |= (h >= s) && (h < e) && (w >= s) && (w < e);
    }
    if (__ballot(needed) == 0ULL) return;   // whole wave dead

    int hs = h - 192;              // F2 source coords (shifted back)
    int ws = w - 192;

    float2 xf[4][3];
    float  mag[4][3];
#pragma unroll
    for (int b = 0; b < 4; ++b) {
        int bp = (b + 2) & 3;
#pragma unroll
        for (int c = 0; c < 3; ++c) {
            int cp = c + 2; if (cp >= 3) cp -= 3;
            float2 v = F2[(size_t)(bp * 3 + cp) * NPIX + (size_t)hs * 384 + ws];
            xf[b][c]  = v;
            mag[b][c] = sqrtf(v.x * v.x + v.y * v.y);
        }
    }

    float lgt[4][9];
#pragma unroll
    for (int b = 0; b < 4; ++b)
#pragma unroll
        for (int j = 0; j < 9; ++j) lgt[b][j] = ab2[j];
    for (int o = 0; o < 64; ++o) {
        float w0 = aw1[o * 3 + 0], w1 = aw1[o * 3 + 1], w2 = aw1[o * 3 + 2];
        float bb = ab1[o];
        float hv[4];
#pragma unroll
        for (int b = 0; b < 4; ++b)
            hv[b] = fmaxf(bb + w0 * mag[b][0] + w1 * mag[b][1] + w2 * mag[b][2], 0.0f);
#pragma unroll
        for (int j = 0; j < 9; ++j) {
            float wj = aw2[j * 64 + o];
#pragma unroll
            for (int b = 0; b < 4; ++b) lgt[b][j] += wj * hv[b];
        }
    }

    float yy = -1.0f + 2.0f * (float)h / 383.0f;
    float xx = -1.0f + 2.0f * (float)w / 383.0f;
    float r   = sqrtf(xx * xx + yy * yy + 1e-6f);
    float phi = atan2f(yy, xx);
    float filt[27];
#pragma unroll
    for (int i = 0; i < 27; ++i) {
        float4 pr = par[i];                 // LDS broadcast
        float lr = logf(r - pr.x);
        float dphi = phi - pr.z;
        filt[i] = expf(lr * lr * pr.y + dphi * dphi * pr.w);
    }

#pragma unroll
    for (int b = 0; b < 4; ++b) {
        float mxv = lgt[b][0];
#pragma unroll
        for (int j = 1; j < 9; ++j) mxv = fmaxf(mxv, lgt[b][j]);
        float e[9];
        float se = 0.0f;
#pragma unroll
        for (int j = 0; j < 9; ++j) { e[j] = expf(lgt[b][j] - mxv); se += e[j]; }
        float inv = 1.0f / se;

        float2 acc = make_float2(0.0f, 0.0f);
#pragma unroll
        for (int d = 0; d < 3; ++d) {
            float wg = 0.0f;
#pragma unroll
            for (int s = 0; s < 3; ++s)
#pragma unroll
                for (int co = 0; co < 3; ++co)
                    wg += e[s * 3 + co] * filt[(s * 3 + co) * 3 + d];
            wg *= inv;
            acc.x += xf[b][d].x * wg;
            acc.y += xf[b][d].y * wg;
        }
        if (needed)
            A[(size_t)b * NPIX + (size_t)h * 384 + w] = acc;
    }
}

// ---------------------------------------------------------------------------
// K4': masked inverse ROW FFTs, band rows only, compact output.
// G1c[ii][h'-sidx][w] stores (-1)^w * row-ifft (unnormalized).
// ---------------------------------------------------------------------------
__global__ __launch_bounds__(256) void k_masked_rows(const float2* __restrict__ A,
                                                     const float* __restrict__ band,
                                                     float2* __restrict__ G1c) {
    int ii  = blockIdx.y;                  // 0..35
    int rg  = blockIdx.x;                  // 0..23
    int cop = ii / 12;
    int bp  = (ii / 3) % 4;
    int dp  = ii % 3;
    int pidx = (cop * 3 + dp) * 2;
    int sidx = (int)floorf((band[pidx + 0] + 1.0f) * 0.5f * 384.0f);
    int eidx = (int)floorf((band[pidx + 1] + 1.0f) * 0.5f * 384.0f);
    if (eidx <= sidx) return;
    int h0 = 192 + rg * 8;
    if (h0 + 8 <= sidx || h0 >= eidx) return;

    __shared__ float2 sbuf[2][LINES * LSTRIDE];
    __shared__ float2 tw[384];
    int tid = threadIdx.x;
    build_tw<256>(tw, tid);
    const float2* Ab = A + (size_t)bp * NPIX;
    for (int idx = tid; idx < 8 * 384; idx += 256) {
        int line = idx / 384;
        int w    = idx - line * 384;
        int h    = h0 + line;
        bool m = (h >= sidx) && (h < eidx) && (w >= sidx) && (w < eidx);
        float2 v = make_float2(0.0f, 0.0f);
        if (m) v = Ab[(size_t)h * 384 + w];
        sbuf[0][line * LSTRIDE + w] = v;
    }
    __syncthreads();
    float2* res = fft384x8<1>(sbuf[0], sbuf[1], tw, tid);
    for (int idx = tid; idx < 8 * 384; idx += 256) {
        int line = idx / 384;
        int w    = idx - line * 384;
        int h    = h0 + line;
        if (h >= sidx && h < eidx) {
            float2 v = res[line * LSTRIDE + w];
            if (w & 1) { v.x = -v.x; v.y = -v.y; }
            G1c[((size_t)ii * 192 + (h - sidx)) * 384 + w] = v;
        }
    }
}

// ---------------------------------------------------------------------------
// K5 (R6): column DFT over band rows + combine + inline 3x3 conv (o=d quirk).
// Register-tiled 4h x 4w per thread. In-loop twiddles via COMPLEX ROTATION:
// t_kh init = tw[(sidx*h)%384], rot_kh = tw[h]; per row t *= rot (4 FMA,
// 4 independent chains) -- no LDS reads, no integer phase ops in the loop.
// 128-thread blocks (grid 72x36) for finer load-balance granularity.
// ---------------------------------------------------------------------------
__global__ __launch_bounds__(128) void k_col_gemm_combine(const float2* __restrict__ G1c,
                                                          const float* __restrict__ band,
                                                          const float* __restrict__ x,
                                                          const float* __restrict__ cw,
                                                          const float* __restrict__ mixing,
                                                          float* __restrict__ out) {
    __shared__ float2 tw[384];
    int tid = threadIdx.x;
    build_tw<128>(tw, tid);

    int ii  = blockIdx.y;
    int gt  = blockIdx.x * 128 + tid;           // 0..9215
    int wq  = gt % 96;
    int hg  = gt / 96;
    int w   = wq * 4;
    int h0  = hg * 4;

    int cop = ii / 12;
    int bp  = (ii / 3) % 4;
    int dp  = ii % 3;
    int pidx = (cop * 3 + dp) * 2;
    int sidx = (int)floorf((band[pidx + 0] + 1.0f) * 0.5f * 384.0f);
    int eidx = (int)floorf((band[pidx + 1] + 1.0f) * 0.5f * 384.0f);
    __syncthreads();

    float acc[4][4];
#pragma unroll
    for (int kh = 0; kh < 4; ++kh)
#pragma unroll
        for (int j = 0; j < 4; ++j) acc[kh][j] = 0.0f;

    // per-kh rotation state (read LDS once; loop is pure FMA)
    float2 t[4], rot[4];
#pragma unroll
    for (int kh = 0; kh < 4; ++kh) {
        int h = h0 + kh;
        t[kh]   = tw[(sidx * h) % 384];
        rot[kh] = tw[h];                        // h < 384
    }

    const float4* g = (const float4*)(G1c + (size_t)ii * 192 * 384 + w);
    for (int hp = sidx; hp < eidx; ++hp) {
        float4 g0 = g[(size_t)(hp - sidx) * 192];       // re0,im0,re1,im1
        float4 g1 = g[(size_t)(hp - sidx) * 192 + 1];   // re2,im2,re3,im3
#pragma unroll
        for (int kh = 0; kh < 4; ++kh) {
            float tx = t[kh].x, ty = t[kh].y;
            acc[kh][0] += tx * g0.x - ty * g0.y;
            acc[kh][1] += tx * g0.z - ty * g0.w;
            acc[kh][2] += tx * g1.x - ty * g1.y;
            acc[kh][3] += tx * g1.z - ty * g1.w;
            t[kh] = make_float2(tx * rot[kh].x - ty * rot[kh].y,
                                tx * rot[kh].y + ty * rot[kh].x);
        }
    }

    int co = cop + 2; if (co >= 3) co -= 3;
    int b  = (bp + 2) & 3;
    int d  = dp + 2;  if (d >= 3) d -= 3;

    // ---- inline 3x3 conv (out channel = d, zero pad), 4x4 tile ----
    float cacc[4][4];
#pragma unroll
    for (int kh = 0; kh < 4; ++kh)
#pragma unroll
        for (int j = 0; j < 4; ++j) cacc[kh][j] = 0.0f;
    const float* xb = x + (size_t)b * 3 * NPIX;
#pragma unroll
    for (int ci = 0; ci < 3; ++ci) {
        const float* xc = xb + (size_t)ci * NPIX;
        const float* w9 = cw + ((size_t)d * 3 + ci) * 9;   // uniform -> scalar loads
        float wv[9];
#pragma unroll
        for (int tt = 0; tt < 9; ++tt) wv[tt] = w9[tt];
#pragma unroll
        for (int ihh = 0; ihh < 6; ++ihh) {
            int hh = h0 - 1 + ihh;
            if (hh < 0 || hh >= 384) continue;
            float v[6];
#pragma unroll
            for (int c6 = 0; c6 < 6; ++c6) {
                int ww = w - 1 + c6;
                v[c6] = (ww >= 0 && ww < 384) ? xc[(size_t)hh * 384 + ww] : 0.0f;
            }
#pragma unroll
            for (int kh = 0; kh < 4; ++kh) {
                int r = ihh - kh;                  // kernel row (compile-time)
                if (r < 0 || r > 2) continue;
#pragma unroll
                for (int j = 0; j < 4; ++j)
#pragma unroll
                    for (int kw = 0; kw < 3; ++kw)
                        cacc[kh][j] += v[j + kw] * wv[r * 3 + kw];
            }
        }
    }

    float mix  = mixing[0];
    float omix = 1.0f - mix;
    const float invn2 = 1.0f / 147456.0f;
    float* obase = out + (size_t)(co * 12 + b * 3 + d) * NPIX;
#pragma unroll
    for (int kh = 0; kh < 4; ++kh) {
        int h = h0 + kh;
        float sgn = (h & 1) ? -invn2 : invn2;           // fold (-1)^h / N^2
        size_t off = (size_t)h * 384 + w;
        float4 val;
        val.x = mix * (acc[kh][0] * sgn) + omix * cacc[kh][0];
        val.y = mix * (acc[kh][1] * sgn) + omix * cacc[kh][1];
        val.z = mix * (acc[kh][2] * sgn) + omix * cacc[kh][2];
        val.w = mix * (acc[kh][3] * sgn) + omix * cacc[kh][3];
#pragma unroll
        for (int a = 0; a < 4; ++a)
            *(float4*)(obase + off + (size_t)a * 5308416) = val;  // a stride = 36*NPIX
    }
}

// ---------------------------------------------------------------------------
extern "C" void kernel_launch(void* const* d_in, const int* in_sizes, int n_in,
                              void* d_out, int out_size, void* d_ws, size_t ws_size,
                              hipStream_t stream) {
    const float* x      = (const float*)d_in[0];
    const float* theta  = (const float*)d_in[1];
    const float* sigma  = (const float*)d_in[2];
    const float* f0     = (const float*)d_in[3];
    const float* theta0 = (const float*)d_in[4];
    const float* aw1    = (const float*)d_in[5];
    const float* ab1    = (const float*)d_in[6];
    const float* aw2    = (const float*)d_in[7];
    const float* ab2    = (const float*)d_in[8];
    const float* cw     = (const float*)d_in[9];
    const float* mixing = (const float*)d_in[10];
    const float* band   = (const float*)d_in[11];
    float* out = (float*)d_out;

    // Workspace layout (float2 units), with reuse:
    //   [0, 12*NPIX)   F1 (dead after K2)   \  overlaid by G1c [0, 18*NPIX)
    //   [12, 24*NPIX)  F2 (dead after K3)   /
    //   [36, 40*NPIX)  A  (attended, shifted frame)
    float2* F1  = (float2*)d_ws;
    float2* F2  = F1 + (size_t)12 * NPIX;
    float2* G1c = (float2*)d_ws;
    float2* A   = (float2*)d_ws + (size_t)36 * NPIX;

    k_fwd_rows<<<dim3(24, 12), 256, 0, stream>>>(x, F1);
    k_fwd_cols<<<dim3(24, 12), 256, 0, stream>>>(F1, F2);
    k_attn<<<192, 192, 0, stream>>>(F2, theta, sigma, f0, theta0,
                                    aw1, ab1, aw2, ab2, band, A);
    k_masked_rows<<<dim3(24, 36), 256, 0, stream>>>(A, band, G1c);
    k_col_gemm_combine<<<dim3(72, 36), 128, 0, stream>>>(G1c, band, x, cw, mixing, out);
}